// Round 5
// baseline (558.663 us; speedup 1.0000x reference)
//
#include <hip/hip_runtime.h>
#include <cstdint>
#include <cstddef>

// LoRALinear: out[T,M] = x[T,N] @ (W + A@B^T)^T + b   (alpha = 8/8 = 1)
// T=8192, M=4096, N=4096, RANK=8, fp32 in/out.
//
// Round-8: break the LDS<->MFMA serialization (measured: wall/iter 10125 cyc
// = MFMA 4966 + LDS 4608, i.e. the two pipes run back-to-back, never
// overlapped, because every ds_read was consumed by the same phase's MFMA
// behind an lgkmcnt(0)). This round: rolling operand prefetch — every
// ds_read is issued >=1 MFMA-subcluster before its consumer, so the
// compiler's dependency-exact counted lgkm waits let the LDS burst execute
// UNDER the matrix burst. No explicit lgkmcnt(0) anywhere.
//
// Register slotting (the enabler, fits the 256-reg/wave cliff):
//   af: 5 pair-slots A0..A4 (40 VGPR), bf: 4 pair-slots B0..B3 (32 VGPR),
//   acc 128 AGPR. Per K-tile MMA order: S(i)=af[i]x all bf (i=0..3,
//   ii-major), then T(j)=bf[j] x af[4..7] (jj-major) so bf slots die
//   one-by-one and next-tile bf prefetch lands in them. Slot liveness is
//   period-2 in K-tiles (even tile af0 in A0, odd tile af'0 in A4); the
//   loop body is one full period (2 K-tiles), all indices static.
//
// Staging skeleton (proven r1/r4): 256x256 tile, BK=64, 8 waves, 128 KiB
// double-buffered LDS, XOR-swizzled (chunk c of row R at c^(R&7), staged
// via pre-swizzled global source). Stages: buf1-A @ph0, buf1-B @ph1,
// confirm vmcnt(0) @ph2-end (the 8 staged loads are the ONLY outstanding
// VMEM; youngest is a full phase old). Symmetric @ph4/ph5/ph6 for buf0.
// WAR audit: buf1-A last ds-read @ph5 (prev iter), staged @ph0 (>=2
// barriers later); buf1-B last read @ph3, staged @ph1; buf0-A last read
// @ph1, staged @ph4; buf0-B last read @ph7 (prev), staged @ph5. All safe.

#define T_DIM 8192
#define M_DIM 4096
#define N_DIM 4096
#define RANK  8

typedef _Float16 f16x8 __attribute__((ext_vector_type(8)));
typedef float    f32x4 __attribute__((ext_vector_type(4)));

// ---------------------------------------------------------------- prep
#define CAST_BLOCKS 16384
__global__ __launch_bounds__(256)
void prep_all(const float* __restrict__ x, const float* __restrict__ W,
              const float* __restrict__ A, const float* __restrict__ B,
              _Float16* __restrict__ Xh, _Float16* __restrict__ Wh) {
    const int bid = blockIdx.x;
    if (bid < CAST_BLOCKS) {
        size_t i = ((size_t)bid * 256 + threadIdx.x) * 8;
        f32x4 v0 = *(const f32x4*)(x + i);
        f32x4 v1 = *(const f32x4*)(x + i + 4);
        f16x8 o;
#pragma unroll
        for (int k = 0; k < 4; ++k) { o[k] = (_Float16)v0[k]; o[4 + k] = (_Float16)v1[k]; }
        *(f16x8*)(Xh + i) = o;
    } else {
        const size_t c = (size_t)(bid - CAST_BLOCKS) * 256 + threadIdx.x;
        const int m  = (int)(c >> 9);
        const int n0 = (int)(c & 511) << 3;
        f32x4 a0 = *(const f32x4*)(A + (size_t)m * RANK);
        f32x4 a1 = *(const f32x4*)(A + (size_t)m * RANK + 4);
        const float* wp = W + (size_t)m * N_DIM + n0;
        f32x4 w0 = *(const f32x4*)wp;
        f32x4 w1 = *(const f32x4*)(wp + 4);
        f16x8 o;
#pragma unroll
        for (int k = 0; k < 8; ++k) {
            const float* Bn = B + (size_t)(n0 + k) * RANK;
            f32x4 b0 = *(const f32x4*)Bn;
            f32x4 b1 = *(const f32x4*)(Bn + 4);
            float d = a0[0]*b0[0] + a0[1]*b0[1] + a0[2]*b0[2] + a0[3]*b0[3]
                    + a1[0]*b1[0] + a1[1]*b1[1] + a1[2]*b1[2] + a1[3]*b1[3];
            float wv = (k < 4) ? w0[k] : w1[k - 4];
            o[k] = (_Float16)(wv + d);
        }
        *(f16x8*)(Wh + (size_t)m * N_DIM + n0) = o;
    }
}

// ---------------------------------------------------------------- GEMM
__device__ static inline void gld16(const _Float16* g, _Float16* l) {
    __builtin_amdgcn_global_load_lds(
        (const __attribute__((address_space(1))) unsigned int*)g,
        (__attribute__((address_space(3))) unsigned int*)l, 16, 0, 0);
}

__global__ __launch_bounds__(512, 2)
void gemm256(const _Float16* __restrict__ Xh, const _Float16* __restrict__ Wh,
             const float* __restrict__ bias, float* __restrict__ out) {
    __shared__ __align__(16) _Float16 lA[2][256 * 64];
    __shared__ __align__(16) _Float16 lB[2][256 * 64];

    const int tid  = threadIdx.x;
    const int lane = tid & 63;
    const int fr   = lane & 15;
    const int fq   = lane >> 4;
    const int w    = tid >> 6;
    const int wr   = w >> 2;      // 0..1  (M)
    const int wcn  = w & 3;       // 0..3  (N)

    const size_t rowX0 = (size_t)blockIdx.y * 256;
    const size_t rowW0 = (size_t)blockIdx.x * 256;

    // staging source addressing (per-thread, kt-invariant, int offsets)
    const int srow = tid >> 3;                                // 0..63
    const int scol = ((tid & 7) * 8) ^ ((srow & 7) * 8);      // pre-swizzled col
    const int aofs = (int)((rowX0 + srow) * N_DIM) + scol;
    int wofs0, wofs1, wofs2, wofs3;
    {
        int t[4];
#pragma unroll
        for (int cb = 0; cb < 4; ++cb) {
            const int p = cb * 64 + srow;
            const int wrow = ((p >> 5) & 3) * 64 + ((p >> 7) & 1) * 32 + (p & 31);
            t[cb] = (int)((rowW0 + wrow) * N_DIM) + scol;
        }
        wofs0 = t[0]; wofs1 = t[1]; wofs2 = t[2]; wofs3 = t[3];
    }

    // fragment-read swizzled column (f16 units); ks=1 flips bit 5
    const int kc0 = (fq * 8) ^ ((fr & 7) * 8);

    f32x4 acc[8][4] = {};
    // operand pair-slots (each pair = ks0,ks1 f16x8)
    f16x8 a0_0, a0_1, a1_0, a1_1, a2_0, a2_1, a3_0, a3_1, a4_0, a4_1;
    f16x8 b0_0, b0_1, b1_0, b1_1, b2_0, b2_1, b3_0, b3_1;

#define STAGE_A(b, rb, kt) gld16(Xh + aofs + (rb) * N_DIM + (kt) * 64, \
                                 &lA[b][(rb) * 64 + tid * 8])
#define STAGE_B0(b, kt) gld16(Wh + wofs0 + (kt) * 64, &lB[b][tid * 8])
#define STAGE_B1(b, kt) gld16(Wh + wofs1 + (kt) * 64, &lB[b][4096 + tid * 8])
#define STAGE_B2(b, kt) gld16(Wh + wofs2 + (kt) * 64, &lB[b][8192 + tid * 8])
#define STAGE_B3(b, kt) gld16(Wh + wofs3 + (kt) * 64, &lB[b][12288 + tid * 8])

// pair-read of A-fragment i (i=0..7) / B-fragment j (j=0..3) from buf b
#define RDA(d0, d1, b, i) do { \
    const int ro_ = (wr * 128 + (i) * 16 + fr) * 64; \
    d0 = *(const f16x8*)&lA[b][ro_ + kc0]; \
    d1 = *(const f16x8*)&lA[b][ro_ + (kc0 ^ 32)]; } while (0)
#define RDB(d0, d1, b, j) do { \
    const int ro_ = (((j) >> 1) * 128 + wcn * 32 + ((j) & 1) * 16 + fr) * 64; \
    d0 = *(const f16x8*)&lB[b][ro_ + kc0]; \
    d1 = *(const f16x8*)&lB[b][ro_ + (kc0 ^ 32)]; } while (0)

#define MF(a, b, c) __builtin_amdgcn_mfma_f32_16x16x32_f16(a, b, c, 0, 0, 0)

// S-subcluster: af pair x all 4 bf pairs -> acc[I][0..3]   (8 MFMA)
#define S8(x0, x1, I) do { \
    acc[I][0] = MF(x0, b0_0, acc[I][0]); acc[I][0] = MF(x1, b0_1, acc[I][0]); \
    acc[I][1] = MF(x0, b1_0, acc[I][1]); acc[I][1] = MF(x1, b1_1, acc[I][1]); \
    acc[I][2] = MF(x0, b2_0, acc[I][2]); acc[I][2] = MF(x1, b2_1, acc[I][2]); \
    acc[I][3] = MF(x0, b3_0, acc[I][3]); acc[I][3] = MF(x1, b3_1, acc[I][3]); } while (0)

// T-subcluster: bf pair x af[4..7] (slots passed) -> acc[4..7][J]  (8 MFMA)
#define T8(y0, y1, J, p40, p41, p50, p51, p60, p61, p70, p71) do { \
    acc[4][J] = MF(p40, y0, acc[4][J]); acc[4][J] = MF(p41, y1, acc[4][J]); \
    acc[5][J] = MF(p50, y0, acc[5][J]); acc[5][J] = MF(p51, y1, acc[5][J]); \
    acc[6][J] = MF(p60, y0, acc[6][J]); acc[6][J] = MF(p61, y1, acc[6][J]); \
    acc[7][J] = MF(p70, y0, acc[7][J]); acc[7][J] = MF(p71, y1, acc[7][J]); } while (0)

// even tile: af4..7 live in A3,A0,A1,A2 ; odd tile: A3,A4,A1,A2
#define T8E(y0, y1, J) T8(y0, y1, J, a3_0, a3_1, a0_0, a0_1, a1_0, a1_1, a2_0, a2_1)
#define T8O(y0, y1, J) T8(y0, y1, J, a3_0, a3_1, a4_0, a4_1, a1_0, a1_1, a2_0, a2_1)

#define BAR   asm volatile("s_barrier" ::: "memory")
#define VW0   asm volatile("s_waitcnt vmcnt(0)" ::: "memory")
#define PRIO1 __builtin_amdgcn_s_setprio(1)
#define PRIO0 __builtin_amdgcn_s_setprio(0)
#define SB    __builtin_amdgcn_sched_barrier(0)

    // ---- prologue: kt0 -> buf0, confirm, preload af0 + bf0..3
    STAGE_A(0, 0, 0); STAGE_A(0, 64, 0); STAGE_A(0, 128, 0); STAGE_A(0, 192, 0);
    STAGE_B0(0, 0); STAGE_B1(0, 0); STAGE_B2(0, 0); STAGE_B3(0, 0);
    VW0; BAR;
    RDA(a0_0, a0_1, 0, 0);
    RDB(b0_0, b0_1, 0, 0); RDB(b1_0, b1_1, 0, 1);
    RDB(b2_0, b2_1, 0, 2); RDB(b3_0, b3_1, 0, 3);

    // ---- main loop: iter n computes kt 2n (buf0, even) and 2n+1 (buf1, odd)
#pragma unroll 1
    for (int n = 0; n < 31; ++n) {
        const int ko  = 2 * n + 1;
        const int ke2 = 2 * n + 2;
        // ph0: prefetch af1,af2,af4; stage buf1-A
        RDA(a1_0, a1_1, 0, 1); RDA(a2_0, a2_1, 0, 2); RDA(a3_0, a3_1, 0, 4);
        STAGE_A(1, 0, ko); STAGE_A(1, 64, ko); STAGE_A(1, 128, ko); STAGE_A(1, 192, ko);
        BAR; PRIO1; S8(a0_0, a0_1, 0); S8(a1_0, a1_1, 1); PRIO0; SB; BAR;
        // ph1: prefetch af3,af5,af6 (+af7 mid); stage buf1-B
        RDA(a4_0, a4_1, 0, 3); RDA(a0_0, a0_1, 0, 5); RDA(a1_0, a1_1, 0, 6);
        STAGE_B0(1, ko); STAGE_B1(1, ko); STAGE_B2(1, ko); STAGE_B3(1, ko);
        BAR; PRIO1; S8(a2_0, a2_1, 2);
        RDA(a2_0, a2_1, 0, 7);
        S8(a4_0, a4_1, 3); PRIO0; SB; BAR;
        // ph2: T(0),T(1); confirm buf1 (its 8 loads are the only outstanding)
        PRIO1; T8E(b0_0, b0_1, 0); T8E(b1_0, b1_1, 1); PRIO0; SB; VW0; BAR;
        // ph3: T(2),T(3); prefetch bf'0..3 + af'0 (buf1, confirmed)
        RDB(b0_0, b0_1, 1, 0); RDB(b1_0, b1_1, 1, 1); RDA(a4_0, a4_1, 1, 0);
        BAR; PRIO1; T8E(b2_0, b2_1, 2);
        RDB(b2_0, b2_1, 1, 2);
        T8E(b3_0, b3_1, 3); PRIO0;
        RDB(b3_0, b3_1, 1, 3);
        SB; BAR;
        // ph4 (odd tile): prefetch af'1,af'2,af'4; stage buf0-A @ke2
        RDA(a1_0, a1_1, 1, 1); RDA(a2_0, a2_1, 1, 2); RDA(a3_0, a3_1, 1, 4);
        STAGE_A(0, 0, ke2); STAGE_A(0, 64, ke2); STAGE_A(0, 128, ke2); STAGE_A(0, 192, ke2);
        BAR; PRIO1; S8(a4_0, a4_1, 0); S8(a1_0, a1_1, 1); PRIO0; SB; BAR;
        // ph5: prefetch af'3,af'5,af'6 (+af'7 mid); stage buf0-B @ke2
        RDA(a0_0, a0_1, 1, 3); RDA(a4_0, a4_1, 1, 5); RDA(a1_0, a1_1, 1, 6);
        STAGE_B0(0, ke2); STAGE_B1(0, ke2); STAGE_B2(0, ke2); STAGE_B3(0, ke2);
        BAR; PRIO1; S8(a2_0, a2_1, 2);
        RDA(a2_0, a2_1, 1, 7);
        S8(a0_0, a0_1, 3); PRIO0; SB; BAR;
        // ph6: T'(0),T'(1); confirm buf0 @ke2
        PRIO1; T8O(b0_0, b0_1, 0); T8O(b1_0, b1_1, 1); PRIO0; SB; VW0; BAR;
        // ph7: T'(2),T'(3); prefetch bf''0..3 + af''0 (buf0 @ke2, confirmed)
        RDB(b0_0, b0_1, 0, 0); RDB(b1_0, b1_1, 0, 1); RDA(a0_0, a0_1, 0, 0);
        BAR; PRIO1; T8O(b2_0, b2_1, 2);
        RDB(b2_0, b2_1, 0, 2);
        T8O(b3_0, b3_1, 3); PRIO0;
        RDB(b3_0, b3_1, 0, 3);
        SB; BAR;
    }

    // ---- tail: kt62 (buf0, even), kt63 (buf1, odd); no kt64 staging/reads
    RDA(a1_0, a1_1, 0, 1); RDA(a2_0, a2_1, 0, 2); RDA(a3_0, a3_1, 0, 4);
    STAGE_A(1, 0, 63); STAGE_A(1, 64, 63); STAGE_A(1, 128, 63); STAGE_A(1, 192, 63);
    BAR; PRIO1; S8(a0_0, a0_1, 0); S8(a1_0, a1_1, 1); PRIO0; SB; BAR;
    RDA(a4_0, a4_1, 0, 3); RDA(a0_0, a0_1, 0, 5); RDA(a1_0, a1_1, 0, 6);
    STAGE_B0(1, 63); STAGE_B1(1, 63); STAGE_B2(1, 63); STAGE_B3(1, 63);
    BAR; PRIO1; S8(a2_0, a2_1, 2);
    RDA(a2_0, a2_1, 0, 7);
    S8(a4_0, a4_1, 3); PRIO0; SB; BAR;
    PRIO1; T8E(b0_0, b0_1, 0); T8E(b1_0, b1_1, 1); PRIO0; SB; VW0; BAR;
    RDB(b0_0, b0_1, 1, 0); RDB(b1_0, b1_1, 1, 1); RDA(a4_0, a4_1, 1, 0);
    BAR; PRIO1; T8E(b2_0, b2_1, 2);
    RDB(b2_0, b2_1, 1, 2);
    T8E(b3_0, b3_1, 3); PRIO0;
    RDB(b3_0, b3_1, 1, 3);
    SB; BAR;
    // odd tile kt63
    RDA(a1_0, a1_1, 1, 1); RDA(a2_0, a2_1, 1, 2); RDA(a3_0, a3_1, 1, 4);
    BAR; PRIO1; S8(a4_0, a4_1, 0); S8(a1_0, a1_1, 1); PRIO0; SB; BAR;
    RDA(a0_0, a0_1, 1, 3); RDA(a4_0, a4_1, 1, 5); RDA(a1_0, a1_1, 1, 6);
    BAR; PRIO1; S8(a2_0, a2_1, 2);
    RDA(a2_0, a2_1, 1, 7);
    S8(a0_0, a0_1, 3); PRIO0; SB; BAR;
    PRIO1; T8O(b0_0, b0_1, 0); T8O(b1_0, b1_1, 1);
    T8O(b2_0, b2_1, 2); T8O(b3_0, b3_1, 3); PRIO0;

    // ---- epilogue: C/D col = lane&15 (out col m), row = (lane>>4)*4 + reg
    {
        const int crow = (int)rowX0 + wr * 128;
        const int ccol = (int)rowW0 + wcn * 64;
        float bv[4];
#pragma unroll
        for (int j = 0; j < 4; ++j) bv[j] = bias[ccol + j * 16 + fr];
#pragma unroll
        for (int i = 0; i < 8; ++i) {
#pragma unroll
            for (int r = 0; r < 4; ++r) {
                const size_t row = (size_t)(crow + i * 16 + fq * 4 + r);
#pragma unroll
                for (int j = 0; j < 4; ++j)
                    out[row * M_DIM + ccol + j * 16 + fr] = acc[i][j][r] + bv[j];
            }
        }
    }
#undef STAGE_A
#undef STAGE_B0
#undef STAGE_B1
#undef STAGE_B2
#undef STAGE_B3
#undef RDA
#undef RDB
#undef MF
#undef S8
#undef T8
#undef T8E
#undef T8O
#undef BAR
#undef VW0
#undef PRIO1
#undef PRIO0
#undef SB
}

// ---------------------------------------------------------------- launch
extern "C" void kernel_launch(void* const* d_in, const int* in_sizes, int n_in,
                              void* d_out, int out_size, void* d_ws, size_t ws_size,
                              hipStream_t stream) {
    const float* x = (const float*)d_in[0];
    const float* W = (const float*)d_in[1];
    const float* b = (const float*)d_in[2];
    const float* A = (const float*)d_in[3];
    const float* B = (const float*)d_in[4];
    float* out = (float*)d_out;

    _Float16* Wh = (_Float16*)d_ws;
    _Float16* Xh = (_Float16*)((char*)d_ws + (size_t)M_DIM * N_DIM * 2);

    prep_all<<<CAST_BLOCKS + (M_DIM * N_DIM / 8) / 256, 256, 0, stream>>>(
        x, W, A, B, Xh, Wh);

    dim3 grid(M_DIM / 256, T_DIM / 256);
    gemm256<<<grid, dim3(512, 1, 1), 0, stream>>>(Xh, Wh, b, out);
}